// Round 9
// baseline (287.311 us; speedup 1.0000x reference)
//
#include <hip/hip_runtime.h>
#include <hip/hip_cooperative_groups.h>
#include <math.h>

namespace cg = cooperative_groups;

// HMM-GLM forward-backward, S=8, N=32, T=262144 — single cooperative kernel.
// transition_matrix = (a-b)*I + b*J exactly => matvec v' = (a-b)v + b*sum(v).
// 256 blocks x 1024 thr, 1 block/CU. Block = 1 group = 16 chunks = 1024 t.
// em/alpha/iemax/rcp(c) live in LDS for the whole pipeline; only the tiny
// group-level matrices (Gf/Gb/supergroup) go through global memory.

constexpr int TT  = 262144;
constexpr int LL  = 64;        // chunk length
constexpr int CK  = TT / LL;   // 4096 chunks
constexpr int CPG = 16;        // chunks per group (= block)
constexpr int NG  = CK / CPG;  // 256 groups = grid size
constexpr int NSG = 16;        // supergroups (16 groups each)
constexpr int EP  = 516;       // padded floats per chunk row in LDS

typedef __attribute__((ext_vector_type(8))) short bf16x8;
typedef __attribute__((ext_vector_type(4))) float f32x4;

__device__ __forceinline__ float rcp_nr(float x) {
  float r = __builtin_amdgcn_rcpf(x);
  return r * (2.0f - x * r);
}
__device__ __forceinline__ unsigned short f2bf(float f) {
  unsigned u = __float_as_uint(f);
  u += 0x7FFFu + ((u >> 16) & 1u);
  return (unsigned short)(u >> 16);
}
__device__ __forceinline__ float bf2f(unsigned short h) {
  return __uint_as_float(((unsigned)h) << 16);
}

#define SWZ8(x, k) __int_as_float(__builtin_amdgcn_ds_swizzle(__float_as_int(x), (((k) << 5) | 0x18)))
#define SWZX(x, d) __int_as_float(__builtin_amdgcn_ds_swizzle(__float_as_int(x), (((d) << 10) | 0x1F)))
#define BPERM(a, x) __int_as_float(__builtin_amdgcn_ds_bpermute((a), __float_as_int(x)))
#define TREE8(dst, v) { float s01=v[0]+v[1], s23=v[2]+v[3], s45=v[4]+v[5], s67=v[6]+v[7]; dst = (s01+s23)+(s45+s67); }

__global__ __launch_bounds__(1024, 4) void k_all(
    const int* __restrict__ spikes, const float* __restrict__ conv,
    const float* __restrict__ W, const float* __restrict__ bias,
    const float* __restrict__ A,
    float* __restrict__ gamma, float* __restrict__ xi,
    float* __restrict__ Gf, float* __restrict__ sgSf, float* __restrict__ sgEf,
    float* __restrict__ Gb, float* __restrict__ sgSb, float* __restrict__ sgEb) {
  cg::grid_group gg = cg::this_grid();

  __shared__ float sEm[16 * EP];      // em [chunk][t*8+s]
  __shared__ float sAl[16 * EP];      // alpha (normalized)
  __shared__ float sIex[16 * 66];     // 1/max_s em
  __shared__ float sRc[16 * 66];      // 1/c_t
  __shared__ unsigned sMask[1024];    // spike masks
  __shared__ short sWbf[256 * 40];    // bf16 W
  __shared__ float sM[16 * 64];       // chunk mats (Pf, then Rb)
  __shared__ float sBf[16 * 8];       // per-chunk entry alpha
  __shared__ float sGbv[16 * 8];      // per-chunk end beta
  __shared__ float sVg[8];            // group entry alpha
  __shared__ float sWgv[8];           // group end beta

  const int tid = threadIdx.x, lane = tid & 63, wv = tid >> 6;
  const int bid = blockIdx.x;
  const float b_ = A[1];
  const float aa = A[0] - b_;         // A = aa*I + b*J
  constexpr float L2E = 1.4426950408889634f;

  // ================= Phase E: emission into LDS =================
#pragma unroll
  for (int it = 0; it < 2; ++it) {
    int idx4 = tid + it * 1024;
    float4 w4 = ((const float4*)W)[idx4];
    int sm = idx4 >> 3, n0 = (idx4 & 7) << 2;
    ushort4 h;
    h.x = f2bf(w4.x); h.y = f2bf(w4.y); h.z = f2bf(w4.z); h.w = f2bf(w4.w);
    *(ushort4*)&sWbf[sm * 40 + n0] = h;
  }
#pragma unroll
  for (int it = 0; it < 32; ++it) {
    int idx = it * 1024 + tid;
    int t = idx >> 5;
    int v = spikes[(size_t)(bid * 1024 + t) * 32 + (idx & 31)];
    unsigned long long bl = __ballot(v != 0);
    if ((lane & 31) == 0) sMask[t] = (unsigned)(bl >> (lane & 32));
  }
  __syncthreads();

  {
    const int q = lane & 15, rg = lane >> 4;
    const float4 bl4 = ((const float4*)bias)[rg];
    const float4 bh4 = ((const float4*)bias)[rg + 4];
    const float bjlo[4] = {bl4.x, bl4.y, bl4.z, bl4.w};
    const float bjhi[4] = {bh4.x, bh4.y, bh4.z, bh4.w};
    const f32x4 zacc = {0.f, 0.f, 0.f, 0.f};
    for (int itt = 0; itt < 4; ++itt) {
      const int tl = itt * 16 + q;                 // local t in chunk wv
      const int Tg = bid * 1024 + wv * 64 + tl;    // global t
      const float* cp = conv + (size_t)Tg * 32 + rg * 8;
      float4 ca = *(const float4*)cp;
      float4 cb = *(const float4*)(cp + 4);
      bf16x8 ch, cfl;
      {
        float cv[8] = {ca.x, ca.y, ca.z, ca.w, cb.x, cb.y, cb.z, cb.w};
#pragma unroll
        for (int e2 = 0; e2 < 8; ++e2) {
          unsigned short hb = f2bf(cv[e2]);
          ch[e2] = (short)hb;
          cfl[e2] = (short)f2bf(cv[e2] - bf2f(hb));
        }
      }
      const unsigned mk = sMask[wv * 64 + tl];
      float e[8];
      float mx = 0.f;
#pragma unroll
      for (int sp = 0; sp < 8; ++sp) {
        bf16x8 wf0 = *(bf16x8*)&sWbf[((2 * sp) * 16 + q) * 40 + rg * 8];
        f32x4 a0 = __builtin_amdgcn_mfma_f32_16x16x32_bf16(wf0, cfl, zacc, 0, 0, 0);
        a0 = __builtin_amdgcn_mfma_f32_16x16x32_bf16(wf0, ch, a0, 0, 0, 0);
        bf16x8 wf1 = *(bf16x8*)&sWbf[((2 * sp + 1) * 16 + q) * 40 + rg * 8];
        f32x4 a1 = __builtin_amdgcn_mfma_f32_16x16x32_bf16(wf1, cfl, zacc, 0, 0, 0);
        a1 = __builtin_amdgcn_mfma_f32_16x16x32_bf16(wf1, ch, a1, 0, 0, 0);
        float sumr = 0.f, pr = 1.f;
#pragma unroll
        for (int r = 0; r < 4; ++r) {
          float z0 = a0[r] + bjlo[r];
          float u0 = __builtin_amdgcn_exp2f(z0 * -L2E);
          float p0 = 1.f + u0;
          sumr += __builtin_amdgcn_rcpf(p0);
          pr *= ((mk >> (rg * 4 + r)) & 1u) ? p0 : 1.f;
          float z1 = a1[r] + bjhi[r];
          float u1 = __builtin_amdgcn_exp2f(z1 * -L2E);
          float p1 = 1.f + u1;
          sumr += __builtin_amdgcn_rcpf(p1);
          pr *= ((mk >> (16 + rg * 4 + r)) & 1u) ? p1 : 1.f;
        }
        float g = fmaf(-L2E, sumr, -__builtin_amdgcn_logf(pr));
        g += SWZX(g, 16);
        g += __shfl_xor(g, 32);
        float ev = fmaxf(__builtin_amdgcn_exp2f(g), 1e-16f);
        e[sp] = ev;
        mx = fmaxf(mx, ev);
      }
      if (lane < 16) {
        float4 o0 = {e[0], e[1], e[2], e[3]};
        float4 o1 = {e[4], e[5], e[6], e[7]};
        *(float4*)&sEm[wv * EP + tl * 8] = o0;
        *(float4*)&sEm[wv * EP + tl * 8 + 4] = o1;
        sIex[wv * 66 + tl] = rcp_nr(mx);
      }
    }
  }
  __syncthreads();

  // ================= P1: fwd chunk products + group product =================
  if (tid < 128) {
    const int cl = tid >> 3, jc = tid & 7;
    float p[8];
#pragma unroll
    for (int k = 0; k < 8; ++k) p[k] = (k == jc) ? 1.f : 0.f;
    const float* eb = &sEm[cl * EP];
    for (int t = 0; t < 64; ++t) {
      float iex = sIex[cl * 66 + t];
      float4 e0 = *(const float4*)&eb[t * 8];
      float4 e1 = *(const float4*)&eb[t * 8 + 4];
      float e[8] = {e0.x * iex, e0.y * iex, e0.z * iex, e0.w * iex,
                    e1.x * iex, e1.y * iex, e1.z * iex, e1.w * iex};
      if (bid == 0 && cl == 0 && t == 0) {
#pragma unroll
        for (int r = 0; r < 8; ++r) p[r] = e[r] * p[r];   // diag(e'_0)*I
      } else {
        float sg; TREE8(sg, p);
        float bs = b_ * sg;
#pragma unroll
        for (int r = 0; r < 8; ++r) p[r] = e[r] * fmaf(aa, p[r], bs);
      }
      if ((t & 7) == 7) {
        float m = p[0];
#pragma unroll
        for (int k = 1; k < 8; ++k) m = fmaxf(m, p[k]);
        m = fmaxf(m, SWZX(m, 1)); m = fmaxf(m, SWZX(m, 2)); m = fmaxf(m, SWZX(m, 4));
        float rm = __builtin_amdgcn_rcpf(m);
#pragma unroll
        for (int k = 0; k < 8; ++k) p[k] *= rm;
      }
    }
#pragma unroll
    for (int r = 0; r < 8; ++r) sM[cl * 64 + r * 8 + jc] = p[r];
  }
  __syncthreads();
  if (tid < 64) {     // group product G = M15 * ... * M0
    const int L = tid;
    int ad[8];
#pragma unroll
    for (int k = 0; k < 8; ++k) ad[k] = (((k << 3) | (L & 7))) << 2;
    float S = sM[L];
#pragma unroll
    for (int m = 1; m < 16; ++m) {
      float4 r0 = *(const float4*)&sM[m * 64 + (L >> 3) * 8];
      float4 r1 = *(const float4*)&sM[m * 64 + (L >> 3) * 8 + 4];
      float acc;
      acc =      r0.x * BPERM(ad[0], S);
      acc = fmaf(r0.y,  BPERM(ad[1], S), acc);
      acc = fmaf(r0.z,  BPERM(ad[2], S), acc);
      acc = fmaf(r0.w,  BPERM(ad[3], S), acc);
      acc = fmaf(r1.x,  BPERM(ad[4], S), acc);
      acc = fmaf(r1.y,  BPERM(ad[5], S), acc);
      acc = fmaf(r1.z,  BPERM(ad[6], S), acc);
      acc = fmaf(r1.w,  BPERM(ad[7], S), acc);
      S = acc;
      if ((m & 3) == 3) {
        float mx = S;
        mx = fmaxf(mx, SWZX(mx, 1));  mx = fmaxf(mx, SWZX(mx, 2));
        mx = fmaxf(mx, SWZX(mx, 4));  mx = fmaxf(mx, SWZX(mx, 8));
        mx = fmaxf(mx, SWZX(mx, 16)); mx = fmaxf(mx, __shfl_xor(mx, 32));
        S *= __builtin_amdgcn_rcpf(mx);
      }
    }
    Gf[(size_t)bid * 64 + L] = S;
  }
  gg.sync();

  // ================= P2: fwd mid-scan (hierarchical) =================
  if (bid < NSG && tid < 64) {   // P2a: supergroup products
    const int L = tid;
    int ad[8];
#pragma unroll
    for (int k = 0; k < 8; ++k) ad[k] = (((k << 3) | (L & 7))) << 2;
    float S = Gf[(size_t)(bid * 16) * 64 + L];
#pragma unroll
    for (int m = 1; m < 16; ++m) {
      const float* mb = &Gf[(size_t)(bid * 16 + m) * 64 + (L >> 3) * 8];
      float4 r0 = *(const float4*)mb;
      float4 r1 = *(const float4*)(mb + 4);
      float acc;
      acc =      r0.x * BPERM(ad[0], S);
      acc = fmaf(r0.y,  BPERM(ad[1], S), acc);
      acc = fmaf(r0.z,  BPERM(ad[2], S), acc);
      acc = fmaf(r0.w,  BPERM(ad[3], S), acc);
      acc = fmaf(r1.x,  BPERM(ad[4], S), acc);
      acc = fmaf(r1.y,  BPERM(ad[5], S), acc);
      acc = fmaf(r1.z,  BPERM(ad[6], S), acc);
      acc = fmaf(r1.w,  BPERM(ad[7], S), acc);
      S = acc;
      if ((m & 3) == 3) {
        float mx = S;
        mx = fmaxf(mx, SWZX(mx, 1));  mx = fmaxf(mx, SWZX(mx, 2));
        mx = fmaxf(mx, SWZX(mx, 4));  mx = fmaxf(mx, SWZX(mx, 8));
        mx = fmaxf(mx, SWZX(mx, 16)); mx = fmaxf(mx, __shfl_xor(mx, 32));
        S *= __builtin_amdgcn_rcpf(mx);
      }
    }
    sgSf[bid * 64 + L] = S;
  }
  gg.sync();
  if (bid == 0 && tid < 64) {    // P2b: scan 16 supergroups
    const int L = tid;
    const int ad2 = ((L & 7) * 9) << 2;
    float vj = 0.125f;
    for (int sg = 0; sg < 16; ++sg) {
      if (L < 8) sgEf[sg * 8 + L] = vj;
      float t = sgSf[sg * 64 + L] * vj;
      t += SWZX(t, 1); t += SWZX(t, 2); t += SWZX(t, 4);
      float t2 = t + SWZX(t, 8); t2 += SWZX(t2, 16); t2 += __shfl_xor(t2, 32);
      vj = BPERM(ad2, t) * rcp_nr(t2);
    }
  }
  gg.sync();
  {                               // P2c: per-block group entry vector
    const int sg = bid >> 4, kk = bid & 15;
    if (tid < 64) {
      const int L = tid;
      const int ad2 = ((L & 7) * 9) << 2;
      float f[15];
#pragma unroll
      for (int m = 0; m < 15; ++m) f[m] = Gf[(size_t)(sg * 16 + m) * 64 + L];
      float vj = sgEf[sg * 8 + (L & 7)];
#pragma unroll
      for (int m = 0; m < 15; ++m) {
        if (m < kk) {
          float t = f[m] * vj;
          t += SWZX(t, 1); t += SWZX(t, 2); t += SWZX(t, 4);
          float t2 = t + SWZX(t, 8); t2 += SWZX(t2, 16); t2 += __shfl_xor(t2, 32);
          vj = BPERM(ad2, t) * rcp_nr(t2);
        }
      }
      if (L < 8) sVg[L] = vj;
    }
  }
  __syncthreads();

  // ================= P3: chunk-bound walk + fwd replay =================
  if (tid < 64) {                 // walk Pf mats (sM) from sVg -> sBf
    const int L = tid;
    const int ad2 = ((L & 7) * 9) << 2;
    float f[16];
#pragma unroll
    for (int m = 0; m < 16; ++m) f[m] = sM[m * 64 + L];
    float vj = sVg[L & 7];
#pragma unroll
    for (int m = 0; m < 16; ++m) {
      if (L < 8) sBf[m * 8 + L] = vj;
      float t = f[m] * vj;
      t += SWZX(t, 1); t += SWZX(t, 2); t += SWZX(t, 4);
      float t2 = t + SWZX(t, 8); t2 += SWZX(t2, 16); t2 += __shfl_xor(t2, 32);
      vj = BPERM(ad2, t) * rcp_nr(t2);
    }
  }
  __syncthreads();
  {                               // fwd replay: wave per chunk, redundant-lane
    float u[8];
#pragma unroll
    for (int k = 0; k < 8; ++k) u[k] = sBf[wv * 8 + k];
    float rs = 1.f;
    const float* eb = &sEm[wv * EP];
#pragma unroll 4
    for (int t = 0; t < 64; ++t) {
      float4 e0 = *(const float4*)&eb[t * 8];
      float4 e1 = *(const float4*)&eb[t * 8 + 4];
      float e[8] = {e0.x, e0.y, e0.z, e0.w, e1.x, e1.y, e1.z, e1.w};
      float un[8];
      if (bid == 0 && wv == 0 && t == 0) {
#pragma unroll
        for (int r = 0; r < 8; ++r) un[r] = 0.125f * e[r];
      } else {
        float sg; TREE8(sg, u);
        float bs = b_ * sg;
#pragma unroll
        for (int r = 0; r < 8; ++r) un[r] = (e[r] * rs) * fmaf(aa, u[r], bs);
      }
      float s; TREE8(s, un);
      float rsn = rcp_nr(s);
      float myu = un[0];
#pragma unroll
      for (int k = 1; k < 8; ++k) myu = (lane == k) ? un[k] : myu;
      if (lane < 8) sAl[wv * EP + t * 8 + lane] = myu * rsn;
      if (lane == 0) sRc[wv * 66 + t] = rsn;
#pragma unroll
      for (int k = 0; k < 8; ++k) u[k] = un[k];
      rs = rsn;
    }
  }
  __syncthreads();

  // ================= P4: bwd chunk products + Gb =================
  {
    const int il = lane & 7;
    float rv[8];
#pragma unroll
    for (int k = 0; k < 8; ++k) rv[k] = (k == il) ? 1.f : 0.f;
    const float* eb = &sEm[wv * EP];
#pragma unroll 4
    for (int t = 0; t < 64; ++t) {
      float rc = sRc[wv * 66 + t];
      float4 d0 = *(const float4*)&eb[t * 8];
      float4 d1 = *(const float4*)&eb[t * 8 + 4];
      float d[8] = {d0.x * rc, d0.y * rc, d0.z * rc, d0.w * rc,
                    d1.x * rc, d1.y * rc, d1.z * rc, d1.w * rc};
      float sg; TREE8(sg, rv);
      float bs = b_ * sg;
#pragma unroll
      for (int j = 0; j < 8; ++j) rv[j] = fmaf(aa, rv[j], bs) * d[j];
    }
    if (lane < 8) {
      float4 o0 = {rv[0], rv[1], rv[2], rv[3]};
      float4 o1 = {rv[4], rv[5], rv[6], rv[7]};
      *(float4*)&sM[wv * 64 + lane * 8] = o0;
      *(float4*)&sM[wv * 64 + lane * 8 + 4] = o1;
    }
  }
  __syncthreads();
  if (tid < 64) {                 // Gb = M0 * M1 * ... * M15 (exact)
    const int L = tid;
    float S = sM[L];
#pragma unroll
    for (int m = 1; m < 16; ++m) {
      const float* mb = &sM[m * 64 + (L & 7)];
      float acc;
      acc =      SWZ8(S, 0) * mb[0];
      acc = fmaf(SWZ8(S, 1), mb[8],  acc);
      acc = fmaf(SWZ8(S, 2), mb[16], acc);
      acc = fmaf(SWZ8(S, 3), mb[24], acc);
      acc = fmaf(SWZ8(S, 4), mb[32], acc);
      acc = fmaf(SWZ8(S, 5), mb[40], acc);
      acc = fmaf(SWZ8(S, 6), mb[48], acc);
      acc = fmaf(SWZ8(S, 7), mb[56], acc);
      S = acc;
    }
    Gb[(size_t)bid * 64 + L] = S;
  }
  gg.sync();

  // ================= P5: bwd mid-scan (hierarchical, exact) =================
  if (bid < NSG && tid < 64) {   // P5a
    const int L = tid;
    float S = Gb[(size_t)(bid * 16) * 64 + L];
#pragma unroll
    for (int m = 1; m < 16; ++m) {
      const float* mb = &Gb[(size_t)(bid * 16 + m) * 64 + (L & 7)];
      float acc;
      acc =      SWZ8(S, 0) * mb[0];
      acc = fmaf(SWZ8(S, 1), mb[8],  acc);
      acc = fmaf(SWZ8(S, 2), mb[16], acc);
      acc = fmaf(SWZ8(S, 3), mb[24], acc);
      acc = fmaf(SWZ8(S, 4), mb[32], acc);
      acc = fmaf(SWZ8(S, 5), mb[40], acc);
      acc = fmaf(SWZ8(S, 6), mb[48], acc);
      acc = fmaf(SWZ8(S, 7), mb[56], acc);
      S = acc;
    }
    sgSb[bid * 64 + L] = S;
  }
  gg.sync();
  if (bid == 0 && tid < 64) {    // P5b
    const int L = tid;
    const int ad2 = ((L & 7) * 9) << 2;
    float wj = 1.f;
    for (int sg = 15; sg >= 0; --sg) {
      if (L < 8) sgEb[sg * 8 + L] = wj;
      float t = sgSb[sg * 64 + L] * wj;
      t += SWZX(t, 1); t += SWZX(t, 2); t += SWZX(t, 4);
      wj = BPERM(ad2, t);
    }
  }
  gg.sync();
  {                               // P5c: per-block group end beta
    const int sg = bid >> 4, kk = bid & 15;
    if (tid < 64) {
      const int L = tid;
      const int ad2 = ((L & 7) * 9) << 2;
      float f[15];
#pragma unroll
      for (int gl = 1; gl < 16; ++gl) f[gl - 1] = Gb[(size_t)(sg * 16 + gl) * 64 + L];
      float wj = sgEb[sg * 8 + (L & 7)];
#pragma unroll
      for (int gl = 15; gl >= 1; --gl) {
        if (gl > kk) {
          float t = f[gl - 1] * wj;
          t += SWZX(t, 1); t += SWZX(t, 2); t += SWZX(t, 4);
          wj = BPERM(ad2, t);
        }
      }
      if (L < 8) sWgv[L] = wj;
    }
  }
  __syncthreads();

  // ================= P6: chunk end-beta walk + bwd replay + epilogue =========
  if (tid < 64) {                 // walk Rb mats (sM) from sWgv -> sGbv
    const int L = tid;
    const int ad2 = ((L & 7) * 9) << 2;
    float f[16];
#pragma unroll
    for (int m = 0; m < 16; ++m) f[m] = sM[m * 64 + L];
    float vj = sWgv[L & 7];
#pragma unroll
    for (int m = 15; m >= 0; --m) {
      if (L < 8) sGbv[m * 8 + L] = vj;
      float t = f[m] * vj;
      t += SWZX(t, 1); t += SWZX(t, 2); t += SWZX(t, 4);
      vj = BPERM(ad2, t);
    }
  }
  __syncthreads();
  {                               // bwd replay: wave per chunk
    const int i = lane >> 3, j = lane & 7;
    const int c = bid * 16 + wv;
    const float Aij = A[i * 8 + j];
    float b = sGbv[wv * 8 + j];
    if (lane < 8) {
      float al = sAl[wv * EP + 63 * 8 + lane];
      gamma[(size_t)(c * 64 + 63) * 8 + lane] = al * b;
    }
#pragma unroll 4
    for (int t = 63; t >= 0; --t) {
      int tg = c * 64 + t;
      float qv = sEm[wv * EP + t * 8 + j] * sRc[wv * 66 + t] * b;
      float apv = (t == 0) ? sBf[wv * 8 + i] : sAl[wv * EP + (t - 1) * 8 + i];
      if (tg > 0) xi[(size_t)(tg - 1) * 64 + lane] = apv * Aij * qv;
      float p = Aij * qv;
      p += SWZX(p, 1); p += SWZX(p, 2); p += SWZX(p, 4);
      if (t > 0 && j == 0) gamma[(size_t)(tg - 1) * 8 + i] = apv * p;
      b = __shfl(p, (lane & 7) * 8);
    }
  }
}

// ---------------------------------------------------------------------------
extern "C" void kernel_launch(void* const* d_in, const int* in_sizes, int n_in,
                              void* d_out, int out_size, void* d_ws, size_t ws_size,
                              hipStream_t stream) {
  const int*   spikes = (const int*)  d_in[0];
  const float* conv   = (const float*)d_in[1];
  const float* W      = (const float*)d_in[2];
  const float* bias   = (const float*)d_in[3];
  const float* A      = (const float*)d_in[4];

  float* out   = (float*)d_out;
  float* gamma = out;                         // T*8
  float* xi    = out + (size_t)TT * 8;        // (T-1)*64

  float* ws    = (float*)d_ws;
  float* Gf    = ws;                          // NG*64
  float* sgSf  = Gf + (size_t)NG * 64;        // NSG*64
  float* sgEf  = sgSf + NSG * 64;             // NSG*8
  float* Gb    = sgEf + NSG * 8;              // NG*64
  float* sgSb  = Gb + (size_t)NG * 64;        // NSG*64
  float* sgEb  = sgSb + NSG * 64;             // NSG*8
  (void)in_sizes; (void)n_in; (void)out_size; (void)ws_size;

  void* args[] = {(void*)&spikes, (void*)&conv, (void*)&W, (void*)&bias,
                  (void*)&A, (void*)&gamma, (void*)&xi,
                  (void*)&Gf, (void*)&sgSf, (void*)&sgEf,
                  (void*)&Gb, (void*)&sgSb, (void*)&sgEb};
  hipLaunchCooperativeKernel((void*)k_all, dim3(NG), dim3(1024), args, 0, stream);
}

// Round 10
// 123.991 us; speedup vs baseline: 2.3172x; 2.3172x over previous
//
#include <hip/hip_runtime.h>
#include <math.h>

// HMM-GLM forward-backward, S=8, N=32, T=262144.
// transition_matrix = (a-b)*I + b*J exactly => matvec v' = (a-b)v + b*sum(v).
// 6 kernels: emission (32x32x16 MFMA: 1 s-tile = 32 m x 32 t, m-reduction
// in-register), fwd chunks(+group product), fwd mid-scan, frbc (fwd replay +
// bwd chunk products fused), bwd mid-scan, bwd replay(+bounds+gamma/xi).
// alpha staged in gamma region of d_out.

constexpr int TT  = 262144;
constexpr int LL  = 64;        // chunk length
constexpr int CK  = TT / LL;   // 4096 chunks
constexpr int CPG = 16;        // chunks per group (= block)
constexpr int NG  = CK / CPG;  // 256 groups
constexpr int NSG = 16;        // supergroups (16 groups each)
constexpr int EP  = 516;       // padded floats per chunk-row in LDS staging

typedef __attribute__((ext_vector_type(8)))  short bf16x8;
typedef __attribute__((ext_vector_type(4)))  float f32x4;
typedef __attribute__((ext_vector_type(16))) float f32x16;

__device__ __forceinline__ float rcp_nr(float x) {
  float r = __builtin_amdgcn_rcpf(x);
  return r * (2.0f - x * r);
}
__device__ __forceinline__ unsigned short f2bf(float f) {
  unsigned u = __float_as_uint(f);
  u += 0x7FFFu + ((u >> 16) & 1u);
  return (unsigned short)(u >> 16);
}
__device__ __forceinline__ float bf2f(unsigned short h) {
  return __uint_as_float(((unsigned)h) << 16);
}

// read lane (groupbase8 | k) within 32-half
#define SWZ8(x, k) __int_as_float(__builtin_amdgcn_ds_swizzle(__float_as_int(x), (((k) << 5) | 0x18)))
// read lane (lane ^ d), d in {1,2,4,8,16}
#define SWZX(x, d) __int_as_float(__builtin_amdgcn_ds_swizzle(__float_as_int(x), (((d) << 10) | 0x1F)))
#define BPERM(a, x) __int_as_float(__builtin_amdgcn_ds_bpermute((a), __float_as_int(x)))

// in-register 8-tree sum
#define TREE8(dst, v) { float s01=v[0]+v[1], s23=v[2]+v[3], s45=v[4]+v[5], s67=v[6]+v[7]; dst = (s01+s23)+(s45+s67); }

// ---------------------------------------------------------------------------
// K1: emission via 32x32x16 MFMA. D[s-tile(32 m)][32 t] = W[s] . conv^T.
// A: row m = lane&31, k=(lane>>5)*8+e. B: col t = lane&31, k=(lane>>5)*8+e.
// D: col t = lane&31, row m = (r&3)+8*(r>>2)+4*(lane>>5), r=0..15.
// Per s: 15 reg-adds + 1 shfl_xor(32) + 1 v_log for the m-reduction.
// Block 256 thr = 4 waves; wave owns 32 t; grid TT/128.
// ---------------------------------------------------------------------------
__global__ __launch_bounds__(256) void k_emission(
    const int* __restrict__ spikes, const float* __restrict__ conv,
    const float* __restrict__ W, const float* __restrict__ bias,
    float* __restrict__ em, float* __restrict__ iemax) {
  __shared__ short sWbf[256 * 40];   // bf16 W, row sm = s*32+m, stride 40
  __shared__ unsigned sMask[128];
  const int tid = threadIdx.x;
  const int lane = tid & 63;
  const int wv = tid >> 6;
  const int T0 = blockIdx.x * 128;
  const int tcol = lane & 31;        // t within the wave's 32-t tile
  const int hi = lane >> 5;          // k-half (A/B), m-half offset (D)

  // stage W as bf16 (coalesced float4 reads)
#pragma unroll
  for (int it = 0; it < 8; ++it) {
    int idx4 = tid + it * 256;       // 2048 float4s = all of W
    float4 w4 = ((const float4*)W)[idx4];
    int sm = idx4 >> 3, n0 = (idx4 & 7) << 2;
    ushort4 h;
    h.x = f2bf(w4.x); h.y = f2bf(w4.y); h.z = f2bf(w4.z); h.w = f2bf(w4.w);
    *(ushort4*)&sWbf[sm * 40 + n0] = h;
  }
  // spike masks via ballot (128 t x 32 n)
#pragma unroll
  for (int it = 0; it < 16; ++it) {
    int idx = it * 256 + tid;
    int t = idx >> 5;
    int v = spikes[(size_t)(T0 + t) * 32 + (idx & 31)];
    unsigned long long b = __ballot(v != 0);
    if ((lane & 31) == 0) sMask[t] = (unsigned)(b >> (lane & 32));
  }
  __syncthreads();

  const int tg = T0 + wv * 32 + tcol;
  // conv fragments (B operand), n-halves 0..15 / 16..31, each split hi/lo
  const float* cp = conv + (size_t)tg * 32 + hi * 8;
  float4 c0a = *(const float4*)cp;
  float4 c0b = *(const float4*)(cp + 4);
  float4 c1a = *(const float4*)(cp + 16);
  float4 c1b = *(const float4*)(cp + 20);
  bf16x8 ch0, cl0, ch1, cl1;
  {
    float cv0[8] = {c0a.x, c0a.y, c0a.z, c0a.w, c0b.x, c0b.y, c0b.z, c0b.w};
    float cv1[8] = {c1a.x, c1a.y, c1a.z, c1a.w, c1b.x, c1b.y, c1b.z, c1b.w};
#pragma unroll
    for (int e2 = 0; e2 < 8; ++e2) {
      unsigned short h0 = f2bf(cv0[e2]);
      ch0[e2] = (short)h0;
      cl0[e2] = (short)f2bf(cv0[e2] - bf2f(h0));
      unsigned short h1 = f2bf(cv1[e2]);
      ch1[e2] = (short)h1;
      cl1[e2] = (short)f2bf(cv1[e2] - bf2f(h1));
    }
  }
  // bias per D-reg slot: m(r) = (r&3) + 8*(r>>2) + 4*hi
  float bj[16];
#pragma unroll
  for (int g = 0; g < 4; ++g) {
    float4 b4 = *(const float4*)&bias[hi * 4 + g * 8];
    bj[g * 4 + 0] = b4.x; bj[g * 4 + 1] = b4.y;
    bj[g * 4 + 2] = b4.z; bj[g * 4 + 3] = b4.w;
  }
  const unsigned mk = sMask[wv * 32 + tcol];
  constexpr float L2E = 1.4426950408889634f;
  f32x16 zacc;
#pragma unroll
  for (int r = 0; r < 16; ++r) zacc[r] = 0.f;

  float e[8];
  float mx = 0.f;
#pragma unroll
  for (int s = 0; s < 8; ++s) {
    bf16x8 A0 = *(bf16x8*)&sWbf[(s * 32 + tcol) * 40 + hi * 8];
    bf16x8 A1 = *(bf16x8*)&sWbf[(s * 32 + tcol) * 40 + 16 + hi * 8];
    f32x16 acc = __builtin_amdgcn_mfma_f32_32x32x16_bf16(A0, cl0, zacc, 0, 0, 0);
    acc = __builtin_amdgcn_mfma_f32_32x32x16_bf16(A1, cl1, acc, 0, 0, 0);
    acc = __builtin_amdgcn_mfma_f32_32x32x16_bf16(A0, ch0, acc, 0, 0, 0);
    acc = __builtin_amdgcn_mfma_f32_32x32x16_bf16(A1, ch1, acc, 0, 0, 0);
    float sumr = 0.f, pr = 1.f;
#pragma unroll
    for (int r = 0; r < 16; ++r) {
      float z = acc[r] + bj[r];
      float u = __builtin_amdgcn_exp2f(z * -L2E);
      float p = 1.f + u;
      sumr += __builtin_amdgcn_rcpf(p);
      int m = (r & 3) + 8 * (r >> 2) + 4 * hi;
      pr *= ((mk >> m) & 1u) ? p : 1.f;
    }
    // g = -log2e*sum(r) - log2(prod(1+u)); partner lane holds other 16 m's
    float g = fmaf(-L2E, sumr, -__builtin_amdgcn_logf(pr));
    g += __shfl_xor(g, 32);
    float ev = fmaxf(__builtin_amdgcn_exp2f(g), 1e-16f);
    e[s] = ev;
    mx = fmaxf(mx, ev);
  }
  if (lane < 32) {
    float4 o0 = {e[0], e[1], e[2], e[3]};
    float4 o1 = {e[4], e[5], e[6], e[7]};
    *(float4*)&em[(size_t)tg * 8] = o0;
    *(float4*)&em[(size_t)tg * 8 + 4] = o1;
    iemax[tg] = rcp_nr(mx);
  }
}

// ---------------------------------------------------------------------------
// K2: fwd chunk products ((a-b),b form) + fused group product. (round 8)
// ---------------------------------------------------------------------------
__global__ __launch_bounds__(128) void k_fwd_chunks(
    const float* __restrict__ em, const float* __restrict__ iemax,
    const float* __restrict__ A, float* __restrict__ Pf,
    float* __restrict__ Gf) {
  __shared__ float sE[16 * EP];
  __shared__ float sM[16 * 64];
  const int tid = threadIdx.x;
  const int cl = tid >> 3, jc = tid & 7;
  const int c = blockIdx.x * 16 + cl;
  const float b_ = A[1];
  const float aa = A[0] - b_;     // A = aa*I + b*J

  for (int idx = tid; idx < 8192; idx += 128) {
    int gi = blockIdx.x * 8192 + idx;
    sE[(idx >> 9) * EP + (idx & 511)] = em[gi] * iemax[gi >> 3];
  }
  __syncthreads();

  float p[8];
#pragma unroll
  for (int k = 0; k < 8; ++k) p[k] = (k == jc) ? 1.f : 0.f;
  const float* eb = &sE[cl * EP];
#pragma unroll 8
  for (int t = 0; t < 64; ++t) {
    float4 e0 = *(const float4*)&eb[t * 8];
    float4 e1 = *(const float4*)&eb[t * 8 + 4];
    float e[8] = {e0.x, e0.y, e0.z, e0.w, e1.x, e1.y, e1.z, e1.w};
    if (c == 0 && t == 0) {
#pragma unroll
      for (int r = 0; r < 8; ++r) p[r] = e[r] * p[r];     // diag(e'_0)*I
    } else {
      float sg; TREE8(sg, p);
      float bs = b_ * sg;
#pragma unroll
      for (int r = 0; r < 8; ++r) p[r] = e[r] * fmaf(aa, p[r], bs);
    }
    if ((t & 7) == 7) {
      float m = p[0];
#pragma unroll
      for (int k = 1; k < 8; ++k) m = fmaxf(m, p[k]);
      m = fmaxf(m, SWZX(m, 1)); m = fmaxf(m, SWZX(m, 2)); m = fmaxf(m, SWZX(m, 4));
      float rm = __builtin_amdgcn_rcpf(m);
#pragma unroll
      for (int k = 0; k < 8; ++k) p[k] *= rm;
    }
  }
#pragma unroll
  for (int r = 0; r < 8; ++r) {
    sM[cl * 64 + r * 8 + jc] = p[r];
    Pf[(size_t)c * 64 + r * 8 + jc] = p[r];
  }
  __syncthreads();

  // wave 0: group product G = M15 * M14 * ... * M0 (left-mult iterative)
  if (tid < 64) {
    const int L = tid;
    int ad[8];
#pragma unroll
    for (int k = 0; k < 8; ++k) ad[k] = (((k << 3) | (L & 7))) << 2;
    float S = sM[L];
    for (int m = 1; m < 16; ++m) {
      float4 r0 = *(const float4*)&sM[m * 64 + (L >> 3) * 8];
      float4 r1 = *(const float4*)&sM[m * 64 + (L >> 3) * 8 + 4];
      float acc;
      acc =      r0.x * BPERM(ad[0], S);
      acc = fmaf(r0.y,  BPERM(ad[1], S), acc);
      acc = fmaf(r0.z,  BPERM(ad[2], S), acc);
      acc = fmaf(r0.w,  BPERM(ad[3], S), acc);
      acc = fmaf(r1.x,  BPERM(ad[4], S), acc);
      acc = fmaf(r1.y,  BPERM(ad[5], S), acc);
      acc = fmaf(r1.z,  BPERM(ad[6], S), acc);
      acc = fmaf(r1.w,  BPERM(ad[7], S), acc);
      S = acc;
      if ((m & 3) == 3) {
        float mx = S;
        mx = fmaxf(mx, SWZX(mx, 1));  mx = fmaxf(mx, SWZX(mx, 2));
        mx = fmaxf(mx, SWZX(mx, 4));  mx = fmaxf(mx, SWZX(mx, 8));
        mx = fmaxf(mx, SWZX(mx, 16)); mx = fmaxf(mx, __shfl_xor(mx, 32));
        S *= __builtin_amdgcn_rcpf(mx);
      }
    }
    Gf[(size_t)blockIdx.x * 64 + L] = S;
  }
}

// ---------------------------------------------------------------------------
// K3: fwd mid-scan (round 8, verified)
// ---------------------------------------------------------------------------
__global__ __launch_bounds__(1024) void k_fwd_mid(
    const float* __restrict__ Gf, float* __restrict__ vg) {
  __shared__ float sG[NG * 64];
  __shared__ float sgS[NSG * 64];
  __shared__ float sgE[NSG * 8];
  const int tid = threadIdx.x, wv = tid >> 6, L = tid & 63;
  for (int idx = tid; idx < NG * 64; idx += 1024) sG[idx] = Gf[idx];
  __syncthreads();

  int ad[8];
#pragma unroll
  for (int k = 0; k < 8; ++k) ad[k] = (((k << 3) | (L & 7))) << 2;
  const int ad2 = ((L & 7) * 9) << 2;

  {
    float S = sG[wv * 1024 + L];
    for (int m = 1; m < 16; ++m) {
      const float* mb = &sG[(wv * 16 + m) * 64 + (L >> 3) * 8];
      float4 r0 = *(const float4*)mb;
      float4 r1 = *(const float4*)(mb + 4);
      float acc;
      acc =      r0.x * BPERM(ad[0], S);
      acc = fmaf(r0.y,  BPERM(ad[1], S), acc);
      acc = fmaf(r0.z,  BPERM(ad[2], S), acc);
      acc = fmaf(r0.w,  BPERM(ad[3], S), acc);
      acc = fmaf(r1.x,  BPERM(ad[4], S), acc);
      acc = fmaf(r1.y,  BPERM(ad[5], S), acc);
      acc = fmaf(r1.z,  BPERM(ad[6], S), acc);
      acc = fmaf(r1.w,  BPERM(ad[7], S), acc);
      S = acc;
      if ((m & 3) == 3) {
        float mx = S;
        mx = fmaxf(mx, SWZX(mx, 1));  mx = fmaxf(mx, SWZX(mx, 2));
        mx = fmaxf(mx, SWZX(mx, 4));  mx = fmaxf(mx, SWZX(mx, 8));
        mx = fmaxf(mx, SWZX(mx, 16)); mx = fmaxf(mx, __shfl_xor(mx, 32));
        S *= __builtin_amdgcn_rcpf(mx);
      }
    }
    sgS[wv * 64 + L] = S;
  }
  __syncthreads();

  if (wv == 0) {
    float vj = 0.125f;
    for (int sg = 0; sg < 16; ++sg) {
      if (L < 8) sgE[sg * 8 + L] = vj;
      float t = sgS[sg * 64 + L] * vj;
      t += SWZX(t, 1); t += SWZX(t, 2); t += SWZX(t, 4);
      float t2 = t + SWZX(t, 8); t2 += SWZX(t2, 16); t2 += __shfl_xor(t2, 32);
      vj = BPERM(ad2, t) * rcp_nr(t2);
    }
  }
  __syncthreads();

  {
    float vj = sgE[wv * 8 + (L & 7)];
    for (int gl = 0; gl < 16; ++gl) {
      int g = wv * 16 + gl;
      if (L < 8) vg[g * 8 + L] = vj;
      float t = sG[g * 64 + L] * vj;
      t += SWZX(t, 1); t += SWZX(t, 2); t += SWZX(t, 4);
      float t2 = t + SWZX(t, 8); t2 += SWZX(t2, 16); t2 += __shfl_xor(t2, 32);
      vj = BPERM(ad2, t) * rcp_nr(t2);
    }
  }
}

// ---------------------------------------------------------------------------
// K4: frbc = fwd replay + bwd chunk products fused (round 8, verified).
// ---------------------------------------------------------------------------
__global__ __launch_bounds__(128) void k_frbc(
    const float* __restrict__ em, const float* __restrict__ A,
    const float* __restrict__ vg, float* __restrict__ bf,
    float* __restrict__ alpha, float* __restrict__ cvec,
    float* __restrict__ PfRb, float* __restrict__ Gb) {
  __shared__ float sE[16 * EP];
  __shared__ float sRC[16 * 66];
  __shared__ float sBf[16 * 8];
  __shared__ float sM[16 * 64];
  const int tid = threadIdx.x;
  const int cl = tid >> 3, jl = tid & 7;
  const int c = blockIdx.x * 16 + cl;
  const float b_ = A[1];
  const float aa = A[0] - b_;     // A = aa*I + b*J

  for (int idx = tid; idx < 8192; idx += 128)
    sE[(idx >> 9) * EP + (idx & 511)] = em[(size_t)blockIdx.x * 8192 + idx];

  if (tid < 64) {
    const int L = tid;
    const int ad2 = ((L & 7) * 9) << 2;
    float f[16];
#pragma unroll
    for (int m = 0; m < 16; ++m) f[m] = PfRb[(size_t)(blockIdx.x * 16 + m) * 64 + L];
    float vj = vg[blockIdx.x * 8 + (L & 7)];
#pragma unroll
    for (int m = 0; m < 16; ++m) {
      if (L < 8) {
        sBf[m * 8 + L] = vj;
        bf[(size_t)(blockIdx.x * 16 + m) * 8 + L] = vj;
      }
      float t = f[m] * vj;
      t += SWZX(t, 1); t += SWZX(t, 2); t += SWZX(t, 4);
      float t2 = t + SWZX(t, 8); t2 += SWZX(t2, 16); t2 += __shfl_xor(t2, 32);
      vj = BPERM(ad2, t) * rcp_nr(t2);
    }
  }
  __syncthreads();

  // phase1: forward replay (redundant-lane)
  {
    float u[8];
#pragma unroll
    for (int k = 0; k < 8; ++k) u[k] = sBf[cl * 8 + k];
    float rs = 1.f;
    const float* eb = &sE[cl * EP];
#pragma unroll 4
    for (int t = 0; t < 64; ++t) {
      float4 e0 = *(const float4*)&eb[t * 8];
      float4 e1 = *(const float4*)&eb[t * 8 + 4];
      float e[8] = {e0.x, e0.y, e0.z, e0.w, e1.x, e1.y, e1.z, e1.w};
      float un[8];
      if (c == 0 && t == 0) {
#pragma unroll
        for (int r = 0; r < 8; ++r) un[r] = 0.125f * e[r];
      } else {
        float sg; TREE8(sg, u);
        float bs = b_ * sg;
#pragma unroll
        for (int r = 0; r < 8; ++r) un[r] = (e[r] * rs) * fmaf(aa, u[r], bs);
      }
      float s; TREE8(s, un);
      float rsn = rcp_nr(s);
      float myu = un[0];
#pragma unroll
      for (int k = 1; k < 8; ++k) myu = (jl == k) ? un[k] : myu;
      int tg = c * 64 + t;
      alpha[(size_t)tg * 8 + jl] = myu * rsn;
      if (jl == 0) { cvec[tg] = s; sRC[cl * 66 + t] = rsn; }
#pragma unroll
      for (int k = 0; k < 8; ++k) u[k] = un[k];
      rs = rsn;
    }
  }
  __syncthreads();

  // phase2: backward chunk products (lane jl = row index), d = em * rcp(c)
  {
    float rv[8];
#pragma unroll
    for (int k = 0; k < 8; ++k) rv[k] = (k == jl) ? 1.f : 0.f;
    const float* eb = &sE[cl * EP];
    const float* rb = &sRC[cl * 66];
#pragma unroll 4
    for (int t = 0; t < 64; ++t) {
      float rc = rb[t];
      float4 d0 = *(const float4*)&eb[t * 8];
      float4 d1 = *(const float4*)&eb[t * 8 + 4];
      float d[8] = {d0.x * rc, d0.y * rc, d0.z * rc, d0.w * rc,
                    d1.x * rc, d1.y * rc, d1.z * rc, d1.w * rc};
      float sg; TREE8(sg, rv);
      float bs = b_ * sg;
#pragma unroll
      for (int j = 0; j < 8; ++j) rv[j] = fmaf(aa, rv[j], bs) * d[j];
    }
    float4 o0 = {rv[0], rv[1], rv[2], rv[3]};
    float4 o1 = {rv[4], rv[5], rv[6], rv[7]};
    *(float4*)&sM[cl * 64 + jl * 8] = o0;
    *(float4*)&sM[cl * 64 + jl * 8 + 4] = o1;
    *(float4*)&PfRb[(size_t)c * 64 + jl * 8] = o0;
    *(float4*)&PfRb[(size_t)c * 64 + jl * 8 + 4] = o1;
  }
  __syncthreads();

  // phase3 (wave0): Gb = M0 * M1 * ... * M15 (right-mult iterative, exact)
  if (tid < 64) {
    const int L = tid;
    float S = sM[L];
    for (int m = 1; m < 16; ++m) {
      const float* mb = &sM[m * 64 + (L & 7)];
      float acc;
      acc =      SWZ8(S, 0) * mb[0];
      acc = fmaf(SWZ8(S, 1), mb[8],  acc);
      acc = fmaf(SWZ8(S, 2), mb[16], acc);
      acc = fmaf(SWZ8(S, 3), mb[24], acc);
      acc = fmaf(SWZ8(S, 4), mb[32], acc);
      acc = fmaf(SWZ8(S, 5), mb[40], acc);
      acc = fmaf(SWZ8(S, 6), mb[48], acc);
      acc = fmaf(SWZ8(S, 7), mb[56], acc);
      S = acc;
    }
    Gb[(size_t)blockIdx.x * 64 + L] = S;
  }
}

// ---------------------------------------------------------------------------
// K5: bwd mid-scan (round 8, verified)
// ---------------------------------------------------------------------------
__global__ __launch_bounds__(1024) void k_bwd_mid(
    const float* __restrict__ Gb, float* __restrict__ wg) {
  __shared__ float sG[NG * 64];
  __shared__ float sgS[NSG * 64];
  __shared__ float sgE[NSG * 8];
  const int tid = threadIdx.x, wv = tid >> 6, L = tid & 63;
  for (int idx = tid; idx < NG * 64; idx += 1024) sG[idx] = Gb[idx];
  __syncthreads();

  const int ad2 = ((L & 7) * 9) << 2;
  {
    float S = sG[wv * 1024 + L];
    for (int m = 1; m < 16; ++m) {
      const float* mb = &sG[(wv * 16 + m) * 64 + (L & 7)];
      float acc;
      acc =      SWZ8(S, 0) * mb[0];
      acc = fmaf(SWZ8(S, 1), mb[8],  acc);
      acc = fmaf(SWZ8(S, 2), mb[16], acc);
      acc = fmaf(SWZ8(S, 3), mb[24], acc);
      acc = fmaf(SWZ8(S, 4), mb[32], acc);
      acc = fmaf(SWZ8(S, 5), mb[40], acc);
      acc = fmaf(SWZ8(S, 6), mb[48], acc);
      acc = fmaf(SWZ8(S, 7), mb[56], acc);
      S = acc;
    }
    sgS[wv * 64 + L] = S;
  }
  __syncthreads();

  if (wv == 0) {
    float wj = 1.f;
    for (int sg = 15; sg >= 0; --sg) {
      if (L < 8) sgE[sg * 8 + L] = wj;
      float t = sgS[sg * 64 + L] * wj;
      t += SWZX(t, 1); t += SWZX(t, 2); t += SWZX(t, 4);
      wj = BPERM(ad2, t);
    }
  }
  __syncthreads();

  {
    float wj = sgE[wv * 8 + (L & 7)];
    for (int gl = 15; gl >= 0; --gl) {
      int g = wv * 16 + gl;
      if (L < 8) wg[g * 8 + L] = wj;
      float t = sG[g * 64 + L] * wj;
      t += SWZX(t, 1); t += SWZX(t, 2); t += SWZX(t, 4);
      wj = BPERM(ad2, t);
    }
  }
}

// ---------------------------------------------------------------------------
// K6: bwd replay + fused bounds + gamma/xi epilogue (round 8, verified).
// ---------------------------------------------------------------------------
__global__ __launch_bounds__(1024) void k_bwd_replay(
    const float* __restrict__ em, const float* __restrict__ cvec,
    const float* __restrict__ A, const float* __restrict__ bf,
    const float* __restrict__ wg, const float* __restrict__ Rb,
    float* __restrict__ gamma, float* __restrict__ xi) {
  __shared__ float sQ[16 * 512];
  __shared__ float sAl[16 * 512];
  __shared__ float sGb[16 * 8];
  const int tid = threadIdx.x, wv = tid >> 6, L = tid & 63;
  const int i = L >> 3, j = L & 7;
  const int c = blockIdx.x * 16 + wv;
  const float Aij = A[i * 8 + j];

  for (int idx = tid; idx < 8192; idx += 1024) {
    int gi = blockIdx.x * 8192 + idx;
    sQ[idx] = em[gi] * rcp_nr(cvec[gi >> 3]);
    int cl2 = idx >> 9, rr = (idx >> 3) & 63, s = idx & 7;
    float av;
    if (rr == 0) av = bf[(blockIdx.x * 16 + cl2) * 8 + s];
    else av = gamma[((size_t)(blockIdx.x * 16 + cl2) * 64 + rr - 1) * 8 + s];
    sAl[idx] = av;
  }
  if (wv == 0) {
    const int ad2 = ((L & 7) * 9) << 2;
    float f[16];
#pragma unroll
    for (int m = 0; m < 16; ++m) f[m] = Rb[(size_t)(blockIdx.x * 16 + m) * 64 + L];
    float vj = wg[blockIdx.x * 8 + (L & 7)];
#pragma unroll
    for (int m = 15; m >= 0; --m) {
      if (L < 8) sGb[m * 8 + L] = vj;
      float t = f[m] * vj;
      t += SWZX(t, 1); t += SWZX(t, 2); t += SWZX(t, 4);
      vj = BPERM(ad2, t);
    }
  }
  __syncthreads();

  float b = sGb[wv * 8 + j];
  {
    int te = c * 64 + 63;
    if (L < 8) {
      float al = gamma[(size_t)te * 8 + L];
      gamma[(size_t)te * 8 + L] = al * b;
    }
  }
#pragma unroll 4
  for (int t = 63; t >= 0; --t) {
    int tg = c * 64 + t;
    float q = sQ[wv * 512 + t * 8 + j] * b;
    float apv = sAl[wv * 512 + t * 8 + i];
    if (tg > 0) xi[(size_t)(tg - 1) * 64 + L] = apv * Aij * q;
    float p = Aij * q;
    p += SWZX(p, 1); p += SWZX(p, 2); p += SWZX(p, 4);
    if (t > 0 && j == 0) gamma[(size_t)(tg - 1) * 8 + i] = apv * p;
    b = __shfl(p, (L & 7) * 8);
  }
}

// ---------------------------------------------------------------------------
extern "C" void kernel_launch(void* const* d_in, const int* in_sizes, int n_in,
                              void* d_out, int out_size, void* d_ws, size_t ws_size,
                              hipStream_t stream) {
  const int*   spikes = (const int*)  d_in[0];
  const float* conv   = (const float*)d_in[1];
  const float* W      = (const float*)d_in[2];
  const float* bias   = (const float*)d_in[3];
  const float* A      = (const float*)d_in[4];

  float* out   = (float*)d_out;
  float* gamma = out;                         // T*8 (alpha, then gamma)
  float* xi    = out + (size_t)TT * 8;        // (T-1)*64

  float* ws    = (float*)d_ws;
  float* em    = ws;                          // T*8
  float* iemax = em + (size_t)TT * 8;         // T
  float* cvec  = iemax + TT;                  // T
  float* Pf    = cvec + TT;                   // CK*64  (becomes Rb in k_frbc)
  float* Rb    = Pf;                          // alias
  float* Gf    = Pf + (size_t)CK * 64;        // NG*64
  float* Gb    = Gf;                          // alias (Gf dead after fwd_mid)
  float* vg    = Gf + NG * 64;                // NG*8
  float* wg    = vg + NG * 8;                 // NG*8
  float* bf    = wg + NG * 8;                 // CK*8
  (void)in_sizes; (void)n_in; (void)out_size; (void)ws_size;

  k_emission  <<<TT / 128, 256, 0, stream>>>(spikes, conv, W, bias, em, iemax);
  k_fwd_chunks<<<NG, 128, 0, stream>>>(em, iemax, A, Pf, Gf);
  k_fwd_mid   <<<1, 1024, 0, stream>>>(Gf, vg);
  k_frbc      <<<NG, 128, 0, stream>>>(em, A, vg, bf, gamma, cvec, Pf, Gb);
  k_bwd_mid   <<<1, 1024, 0, stream>>>(Gb, wg);
  k_bwd_replay<<<NG, 1024, 0, stream>>>(em, cvec, A, bf, wg, Rb, gamma, xi);
}

// Round 11
// 123.373 us; speedup vs baseline: 2.3288x; 1.0050x over previous
//
#include <hip/hip_runtime.h>
#include <math.h>

// HMM-GLM forward-backward, S=8, N=32, T=262144.
// transition_matrix = (a-b)*I + b*J exactly => matvec v' = (a-b)v + b*sum(v).
// 6 kernels: emission (32x32x16 MFMA, bias-in-C, -log2e prescale, 2 indep
// MFMA chains), fwd chunks(+group product), fwd mid-scan, frbc (fwd replay +
// bwd chunk products fused), bwd mid-scan, bwd replay(+bounds+gamma/xi).
// alpha staged in gamma region of d_out.

constexpr int TT  = 262144;
constexpr int LL  = 64;        // chunk length
constexpr int CK  = TT / LL;   // 4096 chunks
constexpr int CPG = 16;        // chunks per group (= block)
constexpr int NG  = CK / CPG;  // 256 groups
constexpr int NSG = 16;        // supergroups (16 groups each)
constexpr int EP  = 516;       // padded floats per chunk-row in LDS staging

typedef __attribute__((ext_vector_type(8)))  short bf16x8;
typedef __attribute__((ext_vector_type(4)))  float f32x4;
typedef __attribute__((ext_vector_type(16))) float f32x16;

__device__ __forceinline__ float rcp_nr(float x) {
  float r = __builtin_amdgcn_rcpf(x);
  return r * (2.0f - x * r);
}
__device__ __forceinline__ unsigned short f2bf(float f) {
  unsigned u = __float_as_uint(f);
  u += 0x7FFFu + ((u >> 16) & 1u);
  return (unsigned short)(u >> 16);
}
__device__ __forceinline__ float bf2f(unsigned short h) {
  return __uint_as_float(((unsigned)h) << 16);
}

// read lane (groupbase8 | k) within 32-half
#define SWZ8(x, k) __int_as_float(__builtin_amdgcn_ds_swizzle(__float_as_int(x), (((k) << 5) | 0x18)))
// read lane (lane ^ d), d in {1,2,4,8,16}
#define SWZX(x, d) __int_as_float(__builtin_amdgcn_ds_swizzle(__float_as_int(x), (((d) << 10) | 0x1F)))
#define BPERM(a, x) __int_as_float(__builtin_amdgcn_ds_bpermute((a), __float_as_int(x)))

// in-register 8-tree sum
#define TREE8(dst, v) { float s01=v[0]+v[1], s23=v[2]+v[3], s45=v[4]+v[5], s67=v[6]+v[7]; dst = (s01+s23)+(s45+s67); }

// ---------------------------------------------------------------------------
// K1: emission via 32x32x16 MFMA. D[s-tile(32 m)][32 t] = W[s] . conv^T.
// conv pre-scaled by -log2e, bias folded into MFMA C => u = exp2(acc) direct.
// Two independent 2-deep MFMA chains (n-halves), merged with 16 adds.
// D: col t = lane&31, row m = (r&3)+8*(r>>2)+4*(lane>>5), r=0..15.
// Block 256 thr = 4 waves; wave owns 32 t; grid TT/128.
// ---------------------------------------------------------------------------
__global__ __launch_bounds__(256) void k_emission(
    const int* __restrict__ spikes, const float* __restrict__ conv,
    const float* __restrict__ W, const float* __restrict__ bias,
    float* __restrict__ em, float* __restrict__ iemax) {
  __shared__ short sWbf[256 * 40];   // bf16 W, row sm = s*32+m, stride 40
  __shared__ unsigned sMask[128];
  const int tid = threadIdx.x;
  const int lane = tid & 63;
  const int wv = tid >> 6;
  const int T0 = blockIdx.x * 128;
  const int tcol = lane & 31;        // t within the wave's 32-t tile
  const int hi = lane >> 5;          // k-half (A/B), m-half offset (D)
  constexpr float L2E  = 1.4426950408889634f;
  constexpr float mL2E = -1.4426950408889634f;

  // stage W as bf16 (coalesced float4 reads)
#pragma unroll
  for (int it = 0; it < 8; ++it) {
    int idx4 = tid + it * 256;       // 2048 float4s = all of W
    float4 w4 = ((const float4*)W)[idx4];
    int sm = idx4 >> 3, n0 = (idx4 & 7) << 2;
    ushort4 h;
    h.x = f2bf(w4.x); h.y = f2bf(w4.y); h.z = f2bf(w4.z); h.w = f2bf(w4.w);
    *(ushort4*)&sWbf[sm * 40 + n0] = h;
  }
  // spike masks via ballot (128 t x 32 n)
#pragma unroll
  for (int it = 0; it < 16; ++it) {
    int idx = it * 256 + tid;
    int t = idx >> 5;
    int v = spikes[(size_t)(T0 + t) * 32 + (idx & 31)];
    unsigned long long b = __ballot(v != 0);
    if ((lane & 31) == 0) sMask[t] = (unsigned)(b >> (lane & 32));
  }
  __syncthreads();

  const int tg = T0 + wv * 32 + tcol;
  // conv fragments (B operand), pre-scaled by -log2e, split hi/lo
  const float* cp = conv + (size_t)tg * 32 + hi * 8;
  float4 c0a = *(const float4*)cp;
  float4 c0b = *(const float4*)(cp + 4);
  float4 c1a = *(const float4*)(cp + 16);
  float4 c1b = *(const float4*)(cp + 20);
  bf16x8 ch0, cl0, ch1, cl1;
  {
    float cv0[8] = {c0a.x, c0a.y, c0a.z, c0a.w, c0b.x, c0b.y, c0b.z, c0b.w};
    float cv1[8] = {c1a.x, c1a.y, c1a.z, c1a.w, c1b.x, c1b.y, c1b.z, c1b.w};
#pragma unroll
    for (int e2 = 0; e2 < 8; ++e2) {
      float s0 = cv0[e2] * mL2E;
      unsigned short h0 = f2bf(s0);
      ch0[e2] = (short)h0;
      cl0[e2] = (short)f2bf(s0 - bf2f(h0));
      float s1 = cv1[e2] * mL2E;
      unsigned short h1 = f2bf(s1);
      ch1[e2] = (short)h1;
      cl1[e2] = (short)f2bf(s1 - bf2f(h1));
    }
  }
  // bias folded into C: Cb[r] = -log2e * bias[m(r)], m(r)=(r&3)+8*(r>>2)+4*hi
  f32x16 cbias;
#pragma unroll
  for (int g = 0; g < 4; ++g) {
    float4 b4 = *(const float4*)&bias[hi * 4 + g * 8];
    cbias[g * 4 + 0] = b4.x * mL2E; cbias[g * 4 + 1] = b4.y * mL2E;
    cbias[g * 4 + 2] = b4.z * mL2E; cbias[g * 4 + 3] = b4.w * mL2E;
  }
  const unsigned mk = sMask[wv * 32 + tcol];
  f32x16 zacc;
#pragma unroll
  for (int r = 0; r < 16; ++r) zacc[r] = 0.f;

  float e[8];
  float mx = 0.f;
#pragma unroll
  for (int s = 0; s < 8; ++s) {
    bf16x8 A0 = *(bf16x8*)&sWbf[(s * 32 + tcol) * 40 + hi * 8];
    bf16x8 A1 = *(bf16x8*)&sWbf[(s * 32 + tcol) * 40 + 16 + hi * 8];
    // two independent 2-deep chains
    f32x16 accA = __builtin_amdgcn_mfma_f32_32x32x16_bf16(A0, cl0, cbias, 0, 0, 0);
    accA = __builtin_amdgcn_mfma_f32_32x32x16_bf16(A0, ch0, accA, 0, 0, 0);
    f32x16 accB = __builtin_amdgcn_mfma_f32_32x32x16_bf16(A1, cl1, zacc, 0, 0, 0);
    accB = __builtin_amdgcn_mfma_f32_32x32x16_bf16(A1, ch1, accB, 0, 0, 0);
    float sumr = 0.f, pr = 1.f;
#pragma unroll
    for (int r = 0; r < 16; ++r) {
      float zz = accA[r] + accB[r];              // = -log2e*(dot+bias)
      float u = __builtin_amdgcn_exp2f(zz);      // e^{-z}
      float p = 1.f + u;
      sumr += __builtin_amdgcn_rcpf(p);
      int m = (r & 3) + 8 * (r >> 2) + 4 * hi;
      pr *= ((mk >> m) & 1u) ? p : 1.f;
    }
    // g = -log2e*sum(r) - log2(prod(1+u)); partner lane holds other 16 m's
    float g = fmaf(mL2E, sumr, -__builtin_amdgcn_logf(pr));
    g += __shfl_xor(g, 32);
    float ev = fmaxf(__builtin_amdgcn_exp2f(g), 1e-16f);
    e[s] = ev;
    mx = fmaxf(mx, ev);
  }
  if (lane < 32) {
    float4 o0 = {e[0], e[1], e[2], e[3]};
    float4 o1 = {e[4], e[5], e[6], e[7]};
    *(float4*)&em[(size_t)tg * 8] = o0;
    *(float4*)&em[(size_t)tg * 8 + 4] = o1;
    iemax[tg] = rcp_nr(mx);
  }
}

// ---------------------------------------------------------------------------
// K2: fwd chunk products ((a-b),b form) + fused group product.
// ---------------------------------------------------------------------------
__global__ __launch_bounds__(128) void k_fwd_chunks(
    const float* __restrict__ em, const float* __restrict__ iemax,
    const float* __restrict__ A, float* __restrict__ Pf,
    float* __restrict__ Gf) {
  __shared__ float sE[16 * EP];
  __shared__ float sM[16 * 64];
  const int tid = threadIdx.x;
  const int cl = tid >> 3, jc = tid & 7;
  const int c = blockIdx.x * 16 + cl;
  const float b_ = A[1];
  const float aa = A[0] - b_;     // A = aa*I + b*J

  for (int idx4 = tid; idx4 < 2048; idx4 += 128) {
    int gi4 = blockIdx.x * 2048 + idx4;
    float4 v = ((const float4*)em)[gi4];
    float ie = iemax[gi4 >> 1];
    v.x *= ie; v.y *= ie; v.z *= ie; v.w *= ie;
    int idx = idx4 * 4;
    *(float4*)&sE[(idx >> 9) * EP + (idx & 511)] = v;
  }
  __syncthreads();

  float p[8];
#pragma unroll
  for (int k = 0; k < 8; ++k) p[k] = (k == jc) ? 1.f : 0.f;
  const float* eb = &sE[cl * EP];
#pragma unroll 8
  for (int t = 0; t < 64; ++t) {
    float4 e0 = *(const float4*)&eb[t * 8];
    float4 e1 = *(const float4*)&eb[t * 8 + 4];
    float e[8] = {e0.x, e0.y, e0.z, e0.w, e1.x, e1.y, e1.z, e1.w};
    if (c == 0 && t == 0) {
#pragma unroll
      for (int r = 0; r < 8; ++r) p[r] = e[r] * p[r];     // diag(e'_0)*I
    } else {
      float sg; TREE8(sg, p);
      float bs = b_ * sg;
#pragma unroll
      for (int r = 0; r < 8; ++r) p[r] = e[r] * fmaf(aa, p[r], bs);
    }
    if ((t & 7) == 7) {
      float m = p[0];
#pragma unroll
      for (int k = 1; k < 8; ++k) m = fmaxf(m, p[k]);
      m = fmaxf(m, SWZX(m, 1)); m = fmaxf(m, SWZX(m, 2)); m = fmaxf(m, SWZX(m, 4));
      float rm = __builtin_amdgcn_rcpf(m);
#pragma unroll
      for (int k = 0; k < 8; ++k) p[k] *= rm;
    }
  }
#pragma unroll
  for (int r = 0; r < 8; ++r) {
    sM[cl * 64 + r * 8 + jc] = p[r];
    Pf[(size_t)c * 64 + r * 8 + jc] = p[r];
  }
  __syncthreads();

  // wave 0: group product G = M15 * M14 * ... * M0 (left-mult iterative)
  if (tid < 64) {
    const int L = tid;
    int ad[8];
#pragma unroll
    for (int k = 0; k < 8; ++k) ad[k] = (((k << 3) | (L & 7))) << 2;
    float S = sM[L];
    for (int m = 1; m < 16; ++m) {
      float4 r0 = *(const float4*)&sM[m * 64 + (L >> 3) * 8];
      float4 r1 = *(const float4*)&sM[m * 64 + (L >> 3) * 8 + 4];
      float acc;
      acc =      r0.x * BPERM(ad[0], S);
      acc = fmaf(r0.y,  BPERM(ad[1], S), acc);
      acc = fmaf(r0.z,  BPERM(ad[2], S), acc);
      acc = fmaf(r0.w,  BPERM(ad[3], S), acc);
      acc = fmaf(r1.x,  BPERM(ad[4], S), acc);
      acc = fmaf(r1.y,  BPERM(ad[5], S), acc);
      acc = fmaf(r1.z,  BPERM(ad[6], S), acc);
      acc = fmaf(r1.w,  BPERM(ad[7], S), acc);
      S = acc;
      if ((m & 3) == 3) {
        float mx = S;
        mx = fmaxf(mx, SWZX(mx, 1));  mx = fmaxf(mx, SWZX(mx, 2));
        mx = fmaxf(mx, SWZX(mx, 4));  mx = fmaxf(mx, SWZX(mx, 8));
        mx = fmaxf(mx, SWZX(mx, 16)); mx = fmaxf(mx, __shfl_xor(mx, 32));
        S *= __builtin_amdgcn_rcpf(mx);
      }
    }
    Gf[(size_t)blockIdx.x * 64 + L] = S;
  }
}

// ---------------------------------------------------------------------------
// K3: fwd mid-scan (round 8, verified)
// ---------------------------------------------------------------------------
__global__ __launch_bounds__(1024) void k_fwd_mid(
    const float* __restrict__ Gf, float* __restrict__ vg) {
  __shared__ float sG[NG * 64];
  __shared__ float sgS[NSG * 64];
  __shared__ float sgE[NSG * 8];
  const int tid = threadIdx.x, wv = tid >> 6, L = tid & 63;
  for (int idx = tid; idx < NG * 64; idx += 1024) sG[idx] = Gf[idx];
  __syncthreads();

  int ad[8];
#pragma unroll
  for (int k = 0; k < 8; ++k) ad[k] = (((k << 3) | (L & 7))) << 2;
  const int ad2 = ((L & 7) * 9) << 2;

  {
    float S = sG[wv * 1024 + L];
    for (int m = 1; m < 16; ++m) {
      const float* mb = &sG[(wv * 16 + m) * 64 + (L >> 3) * 8];
      float4 r0 = *(const float4*)mb;
      float4 r1 = *(const float4*)(mb + 4);
      float acc;
      acc =      r0.x * BPERM(ad[0], S);
      acc = fmaf(r0.y,  BPERM(ad[1], S), acc);
      acc = fmaf(r0.z,  BPERM(ad[2], S), acc);
      acc = fmaf(r0.w,  BPERM(ad[3], S), acc);
      acc = fmaf(r1.x,  BPERM(ad[4], S), acc);
      acc = fmaf(r1.y,  BPERM(ad[5], S), acc);
      acc = fmaf(r1.z,  BPERM(ad[6], S), acc);
      acc = fmaf(r1.w,  BPERM(ad[7], S), acc);
      S = acc;
      if ((m & 3) == 3) {
        float mx = S;
        mx = fmaxf(mx, SWZX(mx, 1));  mx = fmaxf(mx, SWZX(mx, 2));
        mx = fmaxf(mx, SWZX(mx, 4));  mx = fmaxf(mx, SWZX(mx, 8));
        mx = fmaxf(mx, SWZX(mx, 16)); mx = fmaxf(mx, __shfl_xor(mx, 32));
        S *= __builtin_amdgcn_rcpf(mx);
      }
    }
    sgS[wv * 64 + L] = S;
  }
  __syncthreads();

  if (wv == 0) {
    float vj = 0.125f;
    for (int sg = 0; sg < 16; ++sg) {
      if (L < 8) sgE[sg * 8 + L] = vj;
      float t = sgS[sg * 64 + L] * vj;
      t += SWZX(t, 1); t += SWZX(t, 2); t += SWZX(t, 4);
      float t2 = t + SWZX(t, 8); t2 += SWZX(t2, 16); t2 += __shfl_xor(t2, 32);
      vj = BPERM(ad2, t) * rcp_nr(t2);
    }
  }
  __syncthreads();

  {
    float vj = sgE[wv * 8 + (L & 7)];
    for (int gl = 0; gl < 16; ++gl) {
      int g = wv * 16 + gl;
      if (L < 8) vg[g * 8 + L] = vj;
      float t = sG[g * 64 + L] * vj;
      t += SWZX(t, 1); t += SWZX(t, 2); t += SWZX(t, 4);
      float t2 = t + SWZX(t, 8); t2 += SWZX(t2, 16); t2 += __shfl_xor(t2, 32);
      vj = BPERM(ad2, t) * rcp_nr(t2);
    }
  }
}

// ---------------------------------------------------------------------------
// K4: frbc = fwd replay + bwd chunk products fused (round 8, verified;
// staging vectorized).
// ---------------------------------------------------------------------------
__global__ __launch_bounds__(128) void k_frbc(
    const float* __restrict__ em, const float* __restrict__ A,
    const float* __restrict__ vg, float* __restrict__ bf,
    float* __restrict__ alpha, float* __restrict__ cvec,
    float* __restrict__ PfRb, float* __restrict__ Gb) {
  __shared__ float sE[16 * EP];
  __shared__ float sRC[16 * 66];
  __shared__ float sBf[16 * 8];
  __shared__ float sM[16 * 64];
  const int tid = threadIdx.x;
  const int cl = tid >> 3, jl = tid & 7;
  const int c = blockIdx.x * 16 + cl;
  const float b_ = A[1];
  const float aa = A[0] - b_;     // A = aa*I + b*J

  for (int idx4 = tid; idx4 < 2048; idx4 += 128) {
    float4 v = ((const float4*)em)[blockIdx.x * 2048 + idx4];
    int idx = idx4 * 4;
    *(float4*)&sE[(idx >> 9) * EP + (idx & 511)] = v;
  }

  if (tid < 64) {
    const int L = tid;
    const int ad2 = ((L & 7) * 9) << 2;
    float f[16];
#pragma unroll
    for (int m = 0; m < 16; ++m) f[m] = PfRb[(size_t)(blockIdx.x * 16 + m) * 64 + L];
    float vj = vg[blockIdx.x * 8 + (L & 7)];
#pragma unroll
    for (int m = 0; m < 16; ++m) {
      if (L < 8) {
        sBf[m * 8 + L] = vj;
        bf[(size_t)(blockIdx.x * 16 + m) * 8 + L] = vj;
      }
      float t = f[m] * vj;
      t += SWZX(t, 1); t += SWZX(t, 2); t += SWZX(t, 4);
      float t2 = t + SWZX(t, 8); t2 += SWZX(t2, 16); t2 += __shfl_xor(t2, 32);
      vj = BPERM(ad2, t) * rcp_nr(t2);
    }
  }
  __syncthreads();

  // phase1: forward replay (redundant-lane)
  {
    float u[8];
#pragma unroll
    for (int k = 0; k < 8; ++k) u[k] = sBf[cl * 8 + k];
    float rs = 1.f;
    const float* eb = &sE[cl * EP];
#pragma unroll 4
    for (int t = 0; t < 64; ++t) {
      float4 e0 = *(const float4*)&eb[t * 8];
      float4 e1 = *(const float4*)&eb[t * 8 + 4];
      float e[8] = {e0.x, e0.y, e0.z, e0.w, e1.x, e1.y, e1.z, e1.w};
      float un[8];
      if (c == 0 && t == 0) {
#pragma unroll
        for (int r = 0; r < 8; ++r) un[r] = 0.125f * e[r];
      } else {
        float sg; TREE8(sg, u);
        float bs = b_ * sg;
#pragma unroll
        for (int r = 0; r < 8; ++r) un[r] = (e[r] * rs) * fmaf(aa, u[r], bs);
      }
      float s; TREE8(s, un);
      float rsn = rcp_nr(s);
      float myu = un[0];
#pragma unroll
      for (int k = 1; k < 8; ++k) myu = (jl == k) ? un[k] : myu;
      int tg = c * 64 + t;
      alpha[(size_t)tg * 8 + jl] = myu * rsn;
      if (jl == 0) { cvec[tg] = s; sRC[cl * 66 + t] = rsn; }
#pragma unroll
      for (int k = 0; k < 8; ++k) u[k] = un[k];
      rs = rsn;
    }
  }
  __syncthreads();

  // phase2: backward chunk products (lane jl = row index), d = em * rcp(c)
  {
    float rv[8];
#pragma unroll
    for (int k = 0; k < 8; ++k) rv[k] = (k == jl) ? 1.f : 0.f;
    const float* eb = &sE[cl * EP];
    const float* rb = &sRC[cl * 66];
#pragma unroll 4
    for (int t = 0; t < 64; ++t) {
      float rc = rb[t];
      float4 d0 = *(const float4*)&eb[t * 8];
      float4 d1 = *(const float4*)&eb[t * 8 + 4];
      float d[8] = {d0.x * rc, d0.y * rc, d0.z * rc, d0.w * rc,
                    d1.x * rc, d1.y * rc, d1.z * rc, d1.w * rc};
      float sg; TREE8(sg, rv);
      float bs = b_ * sg;
#pragma unroll
      for (int j = 0; j < 8; ++j) rv[j] = fmaf(aa, rv[j], bs) * d[j];
    }
    float4 o0 = {rv[0], rv[1], rv[2], rv[3]};
    float4 o1 = {rv[4], rv[5], rv[6], rv[7]};
    *(float4*)&sM[cl * 64 + jl * 8] = o0;
    *(float4*)&sM[cl * 64 + jl * 8 + 4] = o1;
    *(float4*)&PfRb[(size_t)c * 64 + jl * 8] = o0;
    *(float4*)&PfRb[(size_t)c * 64 + jl * 8 + 4] = o1;
  }
  __syncthreads();

  // phase3 (wave0): Gb = M0 * M1 * ... * M15 (right-mult iterative, exact)
  if (tid < 64) {
    const int L = tid;
    float S = sM[L];
    for (int m = 1; m < 16; ++m) {
      const float* mb = &sM[m * 64 + (L & 7)];
      float acc;
      acc =      SWZ8(S, 0) * mb[0];
      acc = fmaf(SWZ8(S, 1), mb[8],  acc);
      acc = fmaf(SWZ8(S, 2), mb[16], acc);
      acc = fmaf(SWZ8(S, 3), mb[24], acc);
      acc = fmaf(SWZ8(S, 4), mb[32], acc);
      acc = fmaf(SWZ8(S, 5), mb[40], acc);
      acc = fmaf(SWZ8(S, 6), mb[48], acc);
      acc = fmaf(SWZ8(S, 7), mb[56], acc);
      S = acc;
    }
    Gb[(size_t)blockIdx.x * 64 + L] = S;
  }
}

// ---------------------------------------------------------------------------
// K5: bwd mid-scan (round 8, verified)
// ---------------------------------------------------------------------------
__global__ __launch_bounds__(1024) void k_bwd_mid(
    const float* __restrict__ Gb, float* __restrict__ wg) {
  __shared__ float sG[NG * 64];
  __shared__ float sgS[NSG * 64];
  __shared__ float sgE[NSG * 8];
  const int tid = threadIdx.x, wv = tid >> 6, L = tid & 63;
  for (int idx = tid; idx < NG * 64; idx += 1024) sG[idx] = Gb[idx];
  __syncthreads();

  const int ad2 = ((L & 7) * 9) << 2;
  {
    float S = sG[wv * 1024 + L];
    for (int m = 1; m < 16; ++m) {
      const float* mb = &sG[(wv * 16 + m) * 64 + (L & 7)];
      float acc;
      acc =      SWZ8(S, 0) * mb[0];
      acc = fmaf(SWZ8(S, 1), mb[8],  acc);
      acc = fmaf(SWZ8(S, 2), mb[16], acc);
      acc = fmaf(SWZ8(S, 3), mb[24], acc);
      acc = fmaf(SWZ8(S, 4), mb[32], acc);
      acc = fmaf(SWZ8(S, 5), mb[40], acc);
      acc = fmaf(SWZ8(S, 6), mb[48], acc);
      acc = fmaf(SWZ8(S, 7), mb[56], acc);
      S = acc;
    }
    sgS[wv * 64 + L] = S;
  }
  __syncthreads();

  if (wv == 0) {
    float wj = 1.f;
    for (int sg = 15; sg >= 0; --sg) {
      if (L < 8) sgE[sg * 8 + L] = wj;
      float t = sgS[sg * 64 + L] * wj;
      t += SWZX(t, 1); t += SWZX(t, 2); t += SWZX(t, 4);
      wj = BPERM(ad2, t);
    }
  }
  __syncthreads();

  {
    float wj = sgE[wv * 8 + (L & 7)];
    for (int gl = 15; gl >= 0; --gl) {
      int g = wv * 16 + gl;
      if (L < 8) wg[g * 8 + L] = wj;
      float t = sG[g * 64 + L] * wj;
      t += SWZX(t, 1); t += SWZX(t, 2); t += SWZX(t, 4);
      wj = BPERM(ad2, t);
    }
  }
}

// ---------------------------------------------------------------------------
// K6: bwd replay + fused bounds + gamma/xi epilogue (round 8, verified;
// staging vectorized).
// ---------------------------------------------------------------------------
__global__ __launch_bounds__(1024) void k_bwd_replay(
    const float* __restrict__ em, const float* __restrict__ cvec,
    const float* __restrict__ A, const float* __restrict__ bf,
    const float* __restrict__ wg, const float* __restrict__ Rb,
    float* __restrict__ gamma, float* __restrict__ xi) {
  __shared__ float sQ[16 * 512];
  __shared__ float sAl[16 * 512];
  __shared__ float sGb[16 * 8];
  const int tid = threadIdx.x, wv = tid >> 6, L = tid & 63;
  const int i = L >> 3, j = L & 7;
  const int c = blockIdx.x * 16 + wv;
  const float Aij = A[i * 8 + j];

  for (int idx4 = tid; idx4 < 2048; idx4 += 1024) {
    int gi4 = blockIdx.x * 2048 + idx4;
    float4 q4 = ((const float4*)em)[gi4];
    float rc = rcp_nr(cvec[gi4 >> 1]);
    q4.x *= rc; q4.y *= rc; q4.z *= rc; q4.w *= rc;
    *(float4*)&sQ[idx4 * 4] = q4;
    int idx = idx4 * 4;
    int cl2 = idx >> 9, rr = (idx >> 3) & 63, s0 = idx & 7;
    float4 a4;
    if (rr == 0) a4 = *(const float4*)&bf[(blockIdx.x * 16 + cl2) * 8 + s0];
    else a4 = *(const float4*)&gamma[((size_t)(blockIdx.x * 16 + cl2) * 64 + rr - 1) * 8 + s0];
    *(float4*)&sAl[idx4 * 4] = a4;
  }
  if (wv == 0) {
    const int ad2 = ((L & 7) * 9) << 2;
    float f[16];
#pragma unroll
    for (int m = 0; m < 16; ++m) f[m] = Rb[(size_t)(blockIdx.x * 16 + m) * 64 + L];
    float vj = wg[blockIdx.x * 8 + (L & 7)];
#pragma unroll
    for (int m = 15; m >= 0; --m) {
      if (L < 8) sGb[m * 8 + L] = vj;
      float t = f[m] * vj;
      t += SWZX(t, 1); t += SWZX(t, 2); t += SWZX(t, 4);
      vj = BPERM(ad2, t);
    }
  }
  __syncthreads();

  float b = sGb[wv * 8 + j];
  {
    int te = c * 64 + 63;
    if (L < 8) {
      float al = sAl[wv * 512 + 63 * 8 + L];  // alpha[te] staged (rr==63 -> te-1... not te)
      // NOTE: sAl holds alpha[t-1]; alpha[te] must come from gamma directly.
      al = gamma[(size_t)te * 8 + L];
      gamma[(size_t)te * 8 + L] = al * b;
    }
  }
#pragma unroll 4
  for (int t = 63; t >= 0; --t) {
    int tg = c * 64 + t;
    float q = sQ[wv * 512 + t * 8 + j] * b;
    float apv = sAl[wv * 512 + t * 8 + i];
    if (tg > 0) xi[(size_t)(tg - 1) * 64 + L] = apv * Aij * q;
    float p = Aij * q;
    p += SWZX(p, 1); p += SWZX(p, 2); p += SWZX(p, 4);
    if (t > 0 && j == 0) gamma[(size_t)(tg - 1) * 8 + i] = apv * p;
    b = __shfl(p, (L & 7) * 8);
  }
}

// ---------------------------------------------------------------------------
extern "C" void kernel_launch(void* const* d_in, const int* in_sizes, int n_in,
                              void* d_out, int out_size, void* d_ws, size_t ws_size,
                              hipStream_t stream) {
  const int*   spikes = (const int*)  d_in[0];
  const float* conv   = (const float*)d_in[1];
  const float* W      = (const float*)d_in[2];
  const float* bias   = (const float*)d_in[3];
  const float* A      = (const float*)d_in[4];

  float* out   = (float*)d_out;
  float* gamma = out;                         // T*8 (alpha, then gamma)
  float* xi    = out + (size_t)TT * 8;        // (T-1)*64

  float* ws    = (float*)d_ws;
  float* em    = ws;                          // T*8
  float* iemax = em + (size_t)TT * 8;         // T
  float* cvec  = iemax + TT;                  // T
  float* Pf    = cvec + TT;                   // CK*64  (becomes Rb in k_frbc)
  float* Rb    = Pf;                          // alias
  float* Gf    = Pf + (size_t)CK * 64;        // NG*64
  float* Gb    = Gf;                          // alias (Gf dead after fwd_mid)
  float* vg    = Gf + NG * 64;                // NG*8
  float* wg    = vg + NG * 8;                 // NG*8
  float* bf    = wg + NG * 8;                 // CK*8
  (void)in_sizes; (void)n_in; (void)out_size; (void)ws_size;

  k_emission  <<<TT / 128, 256, 0, stream>>>(spikes, conv, W, bias, em, iemax);
  k_fwd_chunks<<<NG, 128, 0, stream>>>(em, iemax, A, Pf, Gf);
  k_fwd_mid   <<<1, 1024, 0, stream>>>(Gf, vg);
  k_frbc      <<<NG, 128, 0, stream>>>(em, A, vg, bf, gamma, cvec, Pf, Gb);
  k_bwd_mid   <<<1, 1024, 0, stream>>>(Gb, wg);
  k_bwd_replay<<<NG, 1024, 0, stream>>>(em, cvec, A, bf, wg, Rb, gamma, xi);
}